// Round 12
// baseline (211.876 us; speedup 1.0000x reference)
//
#include <hip/hip_runtime.h>
#include <hip/hip_bf16.h>

// Pipeline (bf16 internal, fp32 in/out), 4 kernels:
//   prep:   cvt x->xb bf16 [blocks 0,4096) + transpose w_qkv->wqkvT
//           [4096,7168) + w_proj->wprojT [7168,8192). R12: transpose write
//           phase vectorized (ushort2, 2 cols/thread).
//   gemm1:  qkv = xb @ wqkvT^T. R12: DOUBLE-BUFFERED 2-PHASE (T3-minimum):
//           STAGE(buf^1, t+1) issued BEFORE computing buf -> HBM latency
//           hides under MFMA; ONE vmcnt(0)+barrier per K-step (was 2
//           barriers + fully-exposed loads). LDS 128KiB -> 2 blocks/CU.
//           V-col blocks write transposed to vT via LDS bounce. XCD 12x8
//           chunk swizzle, byp-fastest.
//   attn:   flash causal (FROZEN at ~73 µs — latency/convoy floor).
//           k-split QK, 64-row q-tile, 4 waves, grid (16x64), balanced
//           per-CU 4-set qt map, 40KiB LDS -> 4 blocks/CU, reg-prefetch
//           dbuf staging, asm exp2/cvt_pk, l via all-ones-A MFMA.
//   gemm2:  out fp32, 128x64 tile. R12: same dbuf 2-phase (48KiB, 3/CU).
//           XCD 8x8 chunk, byp-fastest.
// WS (32MiB): qkv [0,24M); wqkvT [24,30M); wprojT [30,32M).
// d_out (16MiB): xb bf16 [0,8M); vT [1024][4096] bf16 [8M,16M).
// yb strided into qkv's dead V cols (ld 3072).

typedef unsigned short ushort_t;
typedef __attribute__((ext_vector_type(8))) __bf16 bf16x8;
typedef __attribute__((ext_vector_type(8))) unsigned short ushort8;
typedef __attribute__((ext_vector_type(4))) unsigned short ushort4v;
typedef __attribute__((ext_vector_type(2))) unsigned short ushort2v;
typedef __attribute__((ext_vector_type(4))) float f32x4;

// Swizzled LDS addressing: row stride 64 elems (128B), XOR row bits into
// element bits 3..5 -> b64/b128 column walks hit distinct banks.
#define SWZ(row, e) (((row) << 6) + ((e) ^ (((row) & 7) << 3)))

__device__ inline unsigned short f2bf(float f) {
  union { float f; unsigned int u; } v;
  v.f = f;
  unsigned int r = v.u + 0x7fffu + ((v.u >> 16) & 1u);
  return (unsigned short)(r >> 16);
}

__device__ __forceinline__ float fast_exp2(float x) {
  float r;
  asm("v_exp_f32 %0, %1" : "=v"(r) : "v"(x));  // 2^x, inputs bounded by mask
  return r;
}

__device__ __forceinline__ void gl_lds16(const void* g, void* l) {
  __builtin_amdgcn_global_load_lds((const __attribute__((address_space(1))) void*)g,
                                   (__attribute__((address_space(3))) void*)l, 16, 0, 0);
}

// Fused preprocessing: cvt + two fp32->bf16 transposes (independent work,
// block-uniform branch; __syncthreads only in the transpose range).
__global__ __launch_bounds__(256) void prep(const float* __restrict__ x,
                                            ushort_t* __restrict__ xb,
                                            const float* __restrict__ w_qkv,
                                            ushort_t* __restrict__ wqkvT,
                                            const float* __restrict__ w_proj,
                                            ushort_t* __restrict__ wprojT) {
  const int b = blockIdx.x;
  const int tid = threadIdx.x;
  if (b < 4096) {
    // cvt: x fp32 -> xb bf16, 4 elems/thread
    const size_t i = ((size_t)b * 256 + tid) * 4;
    const float4 v = *(const float4*)(x + i);
    ushort4v o;
    o.x = f2bf(v.x); o.y = f2bf(v.y); o.z = f2bf(v.z); o.w = f2bf(v.w);
    *(ushort4v*)(xb + i) = o;
  } else {
    __shared__ ushort_t tile[32][33];
    const float* in;
    ushort_t* out;
    int R, C, bx, by;
    if (b < 7168) {  // w_qkv [1024][3072] -> wqkvT [3072][1024]
      const int bb = b - 4096;
      bx = bb % 96; by = bb / 96; in = w_qkv; out = wqkvT; R = 1024; C = 3072;
    } else {         // w_proj [1024][1024] -> wprojT [1024][1024]
      const int bb = b - 7168;
      bx = bb % 32; by = bb / 32; in = w_proj; out = wprojT; R = 1024; C = 1024;
    }
    const int r0 = by * 32, c0 = bx * 32;
    const int tx = tid & 31, ty = tid >> 5;  // read: (32,8)
    #pragma unroll
    for (int j = 0; j < 32; j += 8)
      tile[ty + j][tx] = f2bf(in[(size_t)(r0 + ty + j) * C + c0 + tx]);
    __syncthreads();
    // write: (16,16), ushort2 per store (2 consecutive out-cols)
    const int txh = tid & 15, tyw = tid >> 4;
    #pragma unroll
    for (int j = 0; j < 32; j += 16) {
      const int c = tyw + j;  // out row within tile
      ushort2v o;
      o.x = tile[2 * txh][c];
      o.y = tile[2 * txh + 1][c];
      *(ushort2v*)(out + (size_t)(c0 + c) * R + r0 + 2 * txh) = o;
    }
  }
}

// C bf16 = A(bf16) @ Bt^T. Grid fixed (24,32), XCD 12x8 chunk swizzle
// (byp fastest). R12: double-buffered 2-phase K-loop — STAGE next tile
// before computing current; one vmcnt(0)+barrier per K-step.
// Q-scale on bxp<8; bxp>=16 (V cols): write transposed to vT via LDS bounce.
__global__ __launch_bounds__(256, 2) void gemm_bt_bf16out(const ushort_t* __restrict__ A,
                                                          const ushort_t* __restrict__ Bt,
                                                          ushort_t* __restrict__ C,
                                                          ushort_t* __restrict__ vT,
                                                          int M, int N, int K) {
  __shared__ __attribute__((aligned(16))) ushort_t As[2][128 * 64];
  __shared__ __attribute__((aligned(16))) ushort_t Bs[2][128 * 64];
  const int tid = threadIdx.x;
  const int lane = tid & 63;
  const int wave = tid >> 6;
  const int wy = wave >> 1, wx = wave & 1;
  const int quad = lane >> 4, l16 = lane & 15;
  const int bid = blockIdx.y * 24 + blockIdx.x;
  const int xcd = bid & 7, j = bid >> 3;           // j in [0,96)
  const int bxp = (xcd & 1) * 12 + (j >> 3);       // byp fastest
  const int byp = (xcd >> 1) * 8 + (j & 7);
  const size_t bm = (size_t)byp * 128;
  const size_t bn = (size_t)bxp * 128;

  auto stage = [&](int buf, int k0) {
    #pragma unroll
    for (int i = 0; i < 4; ++i) {
      int c = (wave * 4 + i) * 64 + lane;
      int row = c >> 3, col = (c & 7) * 8;
      gl_lds16(A + (bm + row) * K + k0 + col, &As[buf][c * 8]);
      gl_lds16(Bt + (bn + row) * K + k0 + col, &Bs[buf][c * 8]);
    }
  };

  const f32x4 fzero = {0.f, 0.f, 0.f, 0.f};
  f32x4 acc[4][4];
  #pragma unroll
  for (int i = 0; i < 4; ++i)
    #pragma unroll
    for (int jj = 0; jj < 4; ++jj) acc[i][jj] = fzero;

  // prologue: stage tile 0, drain, barrier
  stage(0, 0);
  asm volatile("s_waitcnt vmcnt(0)" ::: "memory");
  __syncthreads();

  int cur = 0;
  for (int k0 = 0; k0 < K; k0 += 64) {
    if (k0 + 64 < K) stage(cur ^ 1, k0 + 64);  // prefetch next (hides under MFMA)
    #pragma unroll
    for (int ks = 0; ks < 2; ++ks) {
      bf16x8 af[4], bb[4];
      #pragma unroll
      for (int mt = 0; mt < 4; ++mt)
        af[mt] = *(const bf16x8*)(&As[cur][(wy * 64 + mt * 16 + l16) * 64 + ks * 32 + quad * 8]);
      #pragma unroll
      for (int nt = 0; nt < 4; ++nt)
        bb[nt] = *(const bf16x8*)(&Bs[cur][(wx * 64 + nt * 16 + l16) * 64 + ks * 32 + quad * 8]);
      __builtin_amdgcn_s_setprio(1);
      #pragma unroll
      for (int mt = 0; mt < 4; ++mt)
        #pragma unroll
        for (int nt = 0; nt < 4; ++nt)
          acc[mt][nt] = __builtin_amdgcn_mfma_f32_16x16x32_bf16(af[mt], bb[nt], acc[mt][nt], 0, 0, 0);
      __builtin_amdgcn_s_setprio(0);
    }
    asm volatile("s_waitcnt vmcnt(0)" ::: "memory");  // next-tile DMA landed
    __syncthreads();                                  // all waves done with buf[cur]
    cur ^= 1;
  }

  if (bxp < 16) {
    // Q/K cols: normal C write (Q scaled)
    const float sc = (bxp < 8) ? 0.18033688f : 1.0f;  // 0.125*log2(e)
    #pragma unroll
    for (int mt = 0; mt < 4; ++mt)
      #pragma unroll
      for (int nt = 0; nt < 4; ++nt)
        #pragma unroll
        for (int r = 0; r < 4; ++r)
          C[(bm + wy * 64 + mt * 16 + quad * 4 + r) * N + bn + wx * 64 + nt * 16 + l16] =
              f2bf(acc[mt][nt][r] * sc);
  } else {
    // V cols: transpose via LDS bounce (two 64-col passes), store to vT.
    // Scratch: flat view of As (16384 ushorts; bounce needs 8704).
    ushort_t* smem = &As[0][0];
    const int vbase = (int)bn - 2048;
    #pragma unroll
    for (int p = 0; p < 2; ++p) {
      if (wx == p) {
        #pragma unroll
        for (int nt = 0; nt < 4; ++nt)
          #pragma unroll
          for (int mt = 0; mt < 4; ++mt)
            #pragma unroll
            for (int i = 0; i < 2; ++i) {
              ushort2v pr;
              pr.x = f2bf(acc[mt][nt][2 * i]);
              pr.y = f2bf(acc[mt][nt][2 * i + 1]);
              *(ushort2v*)(smem + (nt * 16 + l16) * 136 + wy * 64 + mt * 16 + quad * 4 +
                           2 * i) = pr;
            }
      }
      __syncthreads();
      #pragma unroll
      for (int jj = 0; jj < 4; ++jj) {
        int v = (tid >> 4) + jj * 16;
        int row0 = (tid & 15) * 8;
        ushort8 val = *(const ushort8*)(smem + v * 136 + row0);
        *(ushort8*)(vT + (size_t)(vbase + p * 64 + v) * 4096 + bm + row0) = val;
      }
      __syncthreads();
    }
  }
}

// A bf16 [M][K] row stride lda, Bt bf16 [N][K], C fp32. 128x64 tile,
// grid fixed (16,32) = 512 blocks, XCD 8x8 chunk (byp fastest).
// R12: double-buffered 2-phase K-loop (48KiB LDS, 3 blocks/CU).
__global__ __launch_bounds__(256, 3) void gemm_bt_f32out(const ushort_t* __restrict__ A,
                                                         const ushort_t* __restrict__ Bt,
                                                         float* __restrict__ C,
                                                         int M, int N, int K, int lda) {
  __shared__ __attribute__((aligned(16))) ushort_t As[2][128 * 64];
  __shared__ __attribute__((aligned(16))) ushort_t Bs[2][64 * 64];
  const int tid = threadIdx.x;
  const int lane = tid & 63;
  const int wave = tid >> 6;
  const int wy = wave >> 1, wx = wave & 1;  // wave tile: 64 rows x 32 cols
  const int quad = lane >> 4, l16 = lane & 15;
  const int bid = blockIdx.y * 16 + blockIdx.x;
  const int xcd = bid & 7, j = bid >> 3;    // j in [0,64)
  const int bxp = (xcd & 1) * 8 + (j >> 3);  // byp fastest
  const int byp = (xcd >> 1) * 8 + (j & 7);
  const size_t bm = (size_t)byp * 128;
  const size_t bn = (size_t)bxp * 64;

  auto stage = [&](int buf, int k0) {
    #pragma unroll
    for (int i = 0; i < 4; ++i) {
      int c = (wave * 4 + i) * 64 + lane;
      int row = c >> 3, col = (c & 7) * 8;
      gl_lds16(A + (bm + row) * lda + k0 + col, &As[buf][c * 8]);
    }
    #pragma unroll
    for (int i = 0; i < 2; ++i) {
      int c = (wave * 2 + i) * 64 + lane;
      int row = c >> 3, col = (c & 7) * 8;
      gl_lds16(Bt + (bn + row) * K + k0 + col, &Bs[buf][c * 8]);
    }
  };

  const f32x4 fzero = {0.f, 0.f, 0.f, 0.f};
  f32x4 acc[4][2];
  #pragma unroll
  for (int i = 0; i < 4; ++i)
    #pragma unroll
    for (int jj = 0; jj < 2; ++jj) acc[i][jj] = fzero;

  stage(0, 0);
  asm volatile("s_waitcnt vmcnt(0)" ::: "memory");
  __syncthreads();

  int cur = 0;
  for (int k0 = 0; k0 < K; k0 += 64) {
    if (k0 + 64 < K) stage(cur ^ 1, k0 + 64);
    #pragma unroll
    for (int ks = 0; ks < 2; ++ks) {
      bf16x8 af[4], bb[2];
      #pragma unroll
      for (int mt = 0; mt < 4; ++mt)
        af[mt] = *(const bf16x8*)(&As[cur][(wy * 64 + mt * 16 + l16) * 64 + ks * 32 + quad * 8]);
      #pragma unroll
      for (int nt = 0; nt < 2; ++nt)
        bb[nt] = *(const bf16x8*)(&Bs[cur][(wx * 32 + nt * 16 + l16) * 64 + ks * 32 + quad * 8]);
      __builtin_amdgcn_s_setprio(1);
      #pragma unroll
      for (int mt = 0; mt < 4; ++mt)
        #pragma unroll
        for (int nt = 0; nt < 2; ++nt)
          acc[mt][nt] = __builtin_amdgcn_mfma_f32_16x16x32_bf16(af[mt], bb[nt], acc[mt][nt], 0, 0, 0);
      __builtin_amdgcn_s_setprio(0);
    }
    asm volatile("s_waitcnt vmcnt(0)" ::: "memory");
    __syncthreads();
    cur ^= 1;
  }
  #pragma unroll
  for (int mt = 0; mt < 4; ++mt)
    #pragma unroll
    for (int nt = 0; nt < 2; ++nt)
      #pragma unroll
      for (int r = 0; r < 4; ++r)
        C[(bm + wy * 64 + mt * 16 + quad * 4 + r) * N + bn + wx * 32 + nt * 16 + l16] =
            acc[mt][nt][r];
}

// Flash causal attention, k-split QK. FROZEN (R9 structure, ~73 µs floor).
// 64-row q-tile per block, 256 threads = 4 waves. grid (16 heads, 64) =
// 1024 blocks, LDS 40960B -> 4 blocks/CU, 16 waves/CU. Balanced qt mapping:
// CU gets by set {r,r+16,r+32,r+48} -> qt {r, 63-r, 16+r, 47-r}.
// Per iter: [bar1] -> QK k-split (wave w: S^T rows k in w*16..+16, all 64 q;
// 2 ak reads, Q in regs) -> stage t+1 (reg prefetch, 2-iter pipeline) ->
// exp+mask -> Ps write (cross-wave) -> [bar2] -> PV on wave's 16-q strip +
// l via all-ones-A MFMA.
__global__ __launch_bounds__(256, 4) void attn_fwd(const ushort_t* __restrict__ qkv,
                                                   const ushort_t* __restrict__ vT,
                                                   ushort_t* __restrict__ y) {
  __shared__ __attribute__((aligned(16))) ushort_t Ks[2][64 * 64];
  __shared__ __attribute__((aligned(16))) ushort_t Vt[2][64 * 64];
  __shared__ __attribute__((aligned(16))) ushort_t Ps[64 * 64];
  const int head = blockIdx.x;
  const int by = blockIdx.y;
  const int g = by >> 4, r4 = by & 15;  // balanced per-CU 4-set mapping
  const int qt = (g == 0) ? r4 : (g == 1) ? (63 - r4) : (g == 2) ? (16 + r4) : (47 - r4);
  const int qb = qt * 64;
  const int ntiles = qt + 1;
  const int tid = threadIdx.x;
  const int lane = tid & 63, wave = tid >> 6;  // 4 waves
  const int quad = lane >> 4, l16 = lane & 15;
  const int hoff = head * 64;
  const int wrow = wave * 16;                        // wave's k-rows (QK) / q-strip (PV)
  const int srow = tid >> 2, scol = (tid & 3) * 16;  // staging: 64 rows x 64 cols

  // Q fragments for ALL 64 q-rows (B-operand): bq[qtile][ks], 32 VGPRs
  bf16x8 bq[4][2];
  #pragma unroll
  for (int q2 = 0; q2 < 4; ++q2)
    #pragma unroll
    for (int ks = 0; ks < 2; ++ks)
      bq[q2][ks] = *(const bf16x8*)(qkv + (size_t)(qb + q2 * 16 + l16) * 3072 + hoff +
                                    ks * 32 + quad * 8);

  // all-ones A-frag for the l row-sum MFMA
  bf16x8 ones;
  #pragma unroll
  for (int i = 0; i < 8; ++i) ones[i] = (__bf16)1.0f;

  // stage tile 0 into buf0 (reg roundtrip; swizzled ds_write)
  ushort8 kreg[2], vreg[2];
  #pragma unroll
  for (int i = 0; i < 2; ++i) {
    kreg[i] = *(const ushort8*)(qkv + (size_t)srow * 3072 + 1024 + hoff + scol + i * 8);
    vreg[i] = *(const ushort8*)(vT + (size_t)(hoff + srow) * 4096 + scol + i * 8);
  }
  #pragma unroll
  for (int i = 0; i < 2; ++i) {
    *(ushort8*)(Ks[0] + SWZ(srow, scol + i * 8)) = kreg[i];
    *(ushort8*)(Vt[0] + SWZ(srow, scol + i * 8)) = vreg[i];
  }
  // prefetch tile 1 regs (in-bounds even when unused: rows 64..127 < 4096)
  #pragma unroll
  for (int i = 0; i < 2; ++i) {
    kreg[i] = *(const ushort8*)(qkv + (size_t)(64 + srow) * 3072 + 1024 + hoff + scol + i * 8);
    vreg[i] = *(const ushort8*)(vT + (size_t)(hoff + srow) * 4096 + 64 + scol + i * 8);
  }

  const f32x4 fzero = {0.f, 0.f, 0.f, 0.f};
  f32x4 o0[4], ol0 = fzero;
  #pragma unroll
  for (int nt = 0; nt < 4; ++nt) o0[nt] = fzero;

  for (int t = 0; t < ntiles; ++t) {
    const int cur = t & 1;
    __syncthreads();  // bar1: buf[cur] ready; Ps free (prev PV done)

    // QK k-split: S^T[k = wrow+quad*4+r][q = q2*16+l16]; only 2 ak reads
    f32x4 s[4];
    #pragma unroll
    for (int q2 = 0; q2 < 4; ++q2) s[q2] = fzero;
    bf16x8 ak[2];
    #pragma unroll
    for (int ks = 0; ks < 2; ++ks)
      ak[ks] = *(const bf16x8*)(Ks[cur] + SWZ(wrow + l16, ks * 32 + quad * 8));
    __builtin_amdgcn_s_setprio(1);
    #pragma unroll
    for (int ks = 0; ks < 2; ++ks)
      #pragma unroll
      for (int q2 = 0; q2 < 4; ++q2)
        s[q2] = __builtin_amdgcn_mfma_f32_16x16x32_bf16(ak[ks], bq[q2][ks], s[q2], 0, 0, 0);
    __builtin_amdgcn_s_setprio(0);

    // stage tile t+1 into the other buffer; then issue loads for tile t+2
    if (t + 1 < ntiles) {
      #pragma unroll
      for (int i = 0; i < 2; ++i) {
        *(ushort8*)(Ks[1 - cur] + SWZ(srow, scol + i * 8)) = kreg[i];
        *(ushort8*)(Vt[1 - cur] + SWZ(srow, scol + i * 8)) = vreg[i];
      }
      if (t + 2 < ntiles) {
        const int kb2 = (t + 2) * 64;
        #pragma unroll
        for (int i = 0; i < 2; ++i) {
          kreg[i] = *(const ushort8*)(qkv + (size_t)(kb2 + srow) * 3072 + 1024 + hoff +
                                      scol + i * 8);
          vreg[i] = *(const ushort8*)(vT + (size_t)(hoff + srow) * 4096 + kb2 + scol + i * 8);
        }
      }
    }

    // exp + causal mask; write P columns [wrow, wrow+16) for all 64 q.
    // Only the final tile (kb == qb) is masked — block-uniform.
    const int kb = t * 64;
    const bool masked = (kb + 63 > qb);
    #pragma unroll
    for (int q2 = 0; q2 < 4; ++q2) {
      float p[4];
      #pragma unroll
      for (int r = 0; r < 4; ++r) {
        float xv = s[q2][r];
        if (masked) {
          int kkg = kb + wrow + quad * 4 + r;
          xv = (kkg <= qb + q2 * 16 + l16) ? xv : -30000.f;
        }
        p[r] = fast_exp2(xv);
      }
      unsigned int u01, u23;
      asm("v_cvt_pk_bf16_f32 %0, %1, %2" : "=v"(u01) : "v"(p[0]), "v"(p[1]));
      asm("v_cvt_pk_bf16_f32 %0, %1, %2" : "=v"(u23) : "v"(p[2]), "v"(p[3]));
      uint2 pu; pu.x = u01; pu.y = u23;
      *(uint2*)(Ps + SWZ(q2 * 16 + l16, wrow + quad * 4)) = pu;
    }

    __syncthreads();  // bar2: all waves' P columns complete

    // PV on wave's q-strip: O^T += V^T P^T ; l += ones^T P^T
    __builtin_amdgcn_s_setprio(1);
    #pragma unroll
    for (int ks = 0; ks < 2; ++ks) {
      bf16x8 bp0 = *(const bf16x8*)(Ps + SWZ(wrow + l16, ks * 32 + quad * 8));
      #pragma unroll
      for (int nt = 0; nt < 4; ++nt) {
        bf16x8 av = *(const bf16x8*)(Vt[cur] + SWZ(nt * 16 + l16, ks * 32 + quad * 8));
        o0[nt] = __builtin_amdgcn_mfma_f32_16x16x32_bf16(av, bp0, o0[nt], 0, 0, 0);
      }
      ol0 = __builtin_amdgcn_mfma_f32_16x16x32_bf16(ones, bp0, ol0, 0, 0, 0);
    }
    __builtin_amdgcn_s_setprio(0);
  }

  // l[q=l16] is in every row-slot of ol0; no cross-lane reduce needed.
  const float inv0 = 1.0f / ol0[0];
  // o0[nt][r] = O[q = qb+wrow+l16][d = nt*16+quad*4+r] -> packed stores
  #pragma unroll
  for (int nt = 0; nt < 4; ++nt) {
    ushort4v ov0;
    #pragma unroll
    for (int r = 0; r < 4; ++r) ov0[r] = f2bf(o0[nt][r] * inv0);
    *(ushort4v*)(y + (size_t)(qb + wrow + l16) * 3072 + hoff + nt * 16 + quad * 4) = ov0;
  }
}

extern "C" void kernel_launch(void* const* d_in, const int* in_sizes, int n_in,
                              void* d_out, int out_size, void* d_ws, size_t ws_size,
                              hipStream_t stream) {
  const float* x = (const float*)d_in[0];       // [4096][1024] fp32
  const float* w_qkv = (const float*)d_in[1];   // [1024][3072] fp32
  const float* w_proj = (const float*)d_in[2];  // [1024][1024] fp32
  float* out = (float*)d_out;                   // [4096][1024] fp32

  ushort_t* ws = (ushort_t*)d_ws;
  ushort_t* qkv = ws;                            // [4096][3072]  [0, 24 MiB)
  ushort_t* wqkvT = ws + (size_t)4096 * 3072;    // [3072][1024]  [24, 30 MiB)
  ushort_t* wprojT = wqkvT + (size_t)3072 * 1024;  // [1024][1024] [30, 32 MiB)
  ushort_t* yb = qkv + 2048;                     // strided view into dead V cols (ld 3072)
  ushort_t* xb = (ushort_t*)d_out;               // x bf16 in d_out[0,8M)
  ushort_t* vT = (ushort_t*)d_out + (size_t)4096 * 1024;  // [1024][4096] in d_out[8M,16M)

  prep<<<8192, 256, 0, stream>>>(x, xb, w_qkv, wqkvT, w_proj, wprojT);
  gemm_bt_bf16out<<<dim3(24, 32), 256, 0, stream>>>(xb, wqkvT, qkv, vT, 4096, 3072, 1024);
  attn_fwd<<<dim3(16, 64), 256, 0, stream>>>(qkv, vT, yb);
  gemm_bt_f32out<<<dim3(16, 32), 256, 0, stream>>>(yb, wprojT, out, 4096, 1024, 1024, 3072);
}

// Round 13
// 190.136 us; speedup vs baseline: 1.1143x; 1.1143x over previous
//
#include <hip/hip_runtime.h>
#include <hip/hip_bf16.h>

// Pipeline (bf16 internal, fp32 in/out), 4 kernels:
//   prep:   cvt x->xb bf16 [blocks 0,4096) + transpose w_qkv->wqkvT
//           [4096,7168) + w_proj->wprojT [7168,8192); ushort2 writes.
//   gemm1:  qkv = xb @ wqkvT^T (R11 2-barrier loop, 3 blocks/CU). R13:
//           LDS XOR-SWIZZLE (T2) — linear [row][64] tiles were a 16-way
//           bank conflict on every ds_read_b128 (all 16 lanes of a quad at
//           the same 4-bank slot; m201 pattern). Fix per rule #21: linear
//           LDS dst + PRE-SWIZZLED global source granule (colg^(row&7)) +
//           SWZ on read. No schedule/occupancy change vs R11.
//           V-col blocks write transposed to vT via LDS bounce. XCD 12x8
//           chunk swizzle, byp-fastest.
//   attn:   flash causal (FROZEN at ~73 µs — latency/convoy floor).
//           k-split QK, 64-row q-tile, 4 waves, grid (16x64), balanced
//           per-CU 4-set qt map, 40KiB LDS -> 4 blocks/CU, reg-prefetch
//           dbuf staging, asm exp2/cvt_pk, l via all-ones-A MFMA.
//   gemm2:  out fp32, 128x64 tile (R11 loop, 2 blocks/CU) + same swizzle.
//           XCD 8x8 chunk, byp-fastest.
// R12 dbuf-2phase REVERTED (−16 µs regression: occupancy 3->2 + explicit
// vmcnt asm defeating compiler scheduling; m99/m100 lesson).
// WS (32MiB): qkv [0,24M); wqkvT [24,30M); wprojT [30,32M).
// d_out (16MiB): xb bf16 [0,8M); vT [1024][4096] bf16 [8M,16M).
// yb strided into qkv's dead V cols (ld 3072).

typedef unsigned short ushort_t;
typedef __attribute__((ext_vector_type(8))) __bf16 bf16x8;
typedef __attribute__((ext_vector_type(8))) unsigned short ushort8;
typedef __attribute__((ext_vector_type(4))) unsigned short ushort4v;
typedef __attribute__((ext_vector_type(2))) unsigned short ushort2v;
typedef __attribute__((ext_vector_type(4))) float f32x4;

// Swizzled LDS addressing: row stride 64 elems (128B), XOR row bits into
// element bits 3..5 -> b64/b128 column walks hit distinct banks.
#define SWZ(row, e) (((row) << 6) + ((e) ^ (((row) & 7) << 3)))

__device__ inline unsigned short f2bf(float f) {
  union { float f; unsigned int u; } v;
  v.f = f;
  unsigned int r = v.u + 0x7fffu + ((v.u >> 16) & 1u);
  return (unsigned short)(r >> 16);
}

__device__ __forceinline__ float fast_exp2(float x) {
  float r;
  asm("v_exp_f32 %0, %1" : "=v"(r) : "v"(x));  // 2^x, inputs bounded by mask
  return r;
}

__device__ __forceinline__ void gl_lds16(const void* g, void* l) {
  __builtin_amdgcn_global_load_lds((const __attribute__((address_space(1))) void*)g,
                                   (__attribute__((address_space(3))) void*)l, 16, 0, 0);
}

// Fused preprocessing: cvt + two fp32->bf16 transposes (independent work,
// block-uniform branch; __syncthreads only in the transpose range).
__global__ __launch_bounds__(256) void prep(const float* __restrict__ x,
                                            ushort_t* __restrict__ xb,
                                            const float* __restrict__ w_qkv,
                                            ushort_t* __restrict__ wqkvT,
                                            const float* __restrict__ w_proj,
                                            ushort_t* __restrict__ wprojT) {
  const int b = blockIdx.x;
  const int tid = threadIdx.x;
  if (b < 4096) {
    // cvt: x fp32 -> xb bf16, 4 elems/thread
    const size_t i = ((size_t)b * 256 + tid) * 4;
    const float4 v = *(const float4*)(x + i);
    ushort4v o;
    o.x = f2bf(v.x); o.y = f2bf(v.y); o.z = f2bf(v.z); o.w = f2bf(v.w);
    *(ushort4v*)(xb + i) = o;
  } else {
    __shared__ ushort_t tile[32][33];
    const float* in;
    ushort_t* out;
    int R, C, bx, by;
    if (b < 7168) {  // w_qkv [1024][3072] -> wqkvT [3072][1024]
      const int bb = b - 4096;
      bx = bb % 96; by = bb / 96; in = w_qkv; out = wqkvT; R = 1024; C = 3072;
    } else {         // w_proj [1024][1024] -> wprojT [1024][1024]
      const int bb = b - 7168;
      bx = bb % 32; by = bb / 32; in = w_proj; out = wprojT; R = 1024; C = 1024;
    }
    const int r0 = by * 32, c0 = bx * 32;
    const int tx = tid & 31, ty = tid >> 5;  // read: (32,8)
    #pragma unroll
    for (int j = 0; j < 32; j += 8)
      tile[ty + j][tx] = f2bf(in[(size_t)(r0 + ty + j) * C + c0 + tx]);
    __syncthreads();
    // write: (16,16), ushort2 per store (2 consecutive out-cols)
    const int txh = tid & 15, tyw = tid >> 4;
    #pragma unroll
    for (int j = 0; j < 32; j += 16) {
      const int c = tyw + j;  // out row within tile
      ushort2v o;
      o.x = tile[2 * txh][c];
      o.y = tile[2 * txh + 1][c];
      *(ushort2v*)(out + (size_t)(c0 + c) * R + r0 + 2 * txh) = o;
    }
  }
}

// C bf16 = A(bf16) @ Bt^T. Grid fixed (24,32), XCD 12x8 chunk swizzle
// (byp fastest). R11 2-barrier loop + R13 LDS swizzle (pre-swizzled
// global source -> linear LDS dst -> SWZ reads; 16-way -> ~0 conflicts).
// Q-scale on bxp<8; bxp>=16 (V cols): write transposed to vT via LDS bounce.
__global__ __launch_bounds__(256, 3) void gemm_bt_bf16out(const ushort_t* __restrict__ A,
                                                          const ushort_t* __restrict__ Bt,
                                                          ushort_t* __restrict__ C,
                                                          ushort_t* __restrict__ vT,
                                                          int M, int N, int K) {
  __shared__ __attribute__((aligned(16))) ushort_t smem[128 * 64 * 2];
  ushort_t* As = smem;
  ushort_t* Bs = smem + 128 * 64;
  const int tid = threadIdx.x;
  const int lane = tid & 63;
  const int wave = tid >> 6;
  const int wy = wave >> 1, wx = wave & 1;
  const int quad = lane >> 4, l16 = lane & 15;
  const int bid = blockIdx.y * 24 + blockIdx.x;
  const int xcd = bid & 7, j = bid >> 3;           // j in [0,96)
  const int bxp = (xcd & 1) * 12 + (j >> 3);       // byp fastest
  const int byp = (xcd >> 1) * 8 + (j & 7);
  const size_t bm = (size_t)byp * 128;
  const size_t bn = (size_t)bxp * 128;

  const f32x4 fzero = {0.f, 0.f, 0.f, 0.f};
  f32x4 acc[4][4];
  #pragma unroll
  for (int i = 0; i < 4; ++i)
    #pragma unroll
    for (int jj = 0; jj < 4; ++jj) acc[i][jj] = fzero;

  for (int k0 = 0; k0 < K; k0 += 64) {
    #pragma unroll
    for (int i = 0; i < 4; ++i) {
      int c = (wave * 4 + i) * 64 + lane;
      int row = c >> 3, colg = c & 7;
      int scol = (colg ^ (row & 7)) * 8;  // pre-swizzled source granule
      gl_lds16(A + (bm + row) * K + k0 + scol, As + c * 8);
      gl_lds16(Bt + (bn + row) * K + k0 + scol, Bs + c * 8);
    }
    __syncthreads();
    #pragma unroll
    for (int ks = 0; ks < 2; ++ks) {
      bf16x8 af[4], bb[4];
      #pragma unroll
      for (int mt = 0; mt < 4; ++mt)
        af[mt] = *(const bf16x8*)(As + SWZ(wy * 64 + mt * 16 + l16, ks * 32 + quad * 8));
      #pragma unroll
      for (int nt = 0; nt < 4; ++nt)
        bb[nt] = *(const bf16x8*)(Bs + SWZ(wx * 64 + nt * 16 + l16, ks * 32 + quad * 8));
      #pragma unroll
      for (int mt = 0; mt < 4; ++mt)
        #pragma unroll
        for (int nt = 0; nt < 4; ++nt)
          acc[mt][nt] = __builtin_amdgcn_mfma_f32_16x16x32_bf16(af[mt], bb[nt], acc[mt][nt], 0, 0, 0);
    }
    __syncthreads();
  }

  if (bxp < 16) {
    // Q/K cols: normal C write (Q scaled)
    const float sc = (bxp < 8) ? 0.18033688f : 1.0f;  // 0.125*log2(e)
    #pragma unroll
    for (int mt = 0; mt < 4; ++mt)
      #pragma unroll
      for (int nt = 0; nt < 4; ++nt)
        #pragma unroll
        for (int r = 0; r < 4; ++r)
          C[(bm + wy * 64 + mt * 16 + quad * 4 + r) * N + bn + wx * 64 + nt * 16 + l16] =
              f2bf(acc[mt][nt][r] * sc);
  } else {
    // V cols: transpose via LDS bounce (two 64-col passes), store to vT.
    const int vbase = (int)bn - 2048;
    #pragma unroll
    for (int p = 0; p < 2; ++p) {
      if (wx == p) {
        #pragma unroll
        for (int nt = 0; nt < 4; ++nt)
          #pragma unroll
          for (int mt = 0; mt < 4; ++mt)
            #pragma unroll
            for (int i = 0; i < 2; ++i) {
              ushort2v pr;
              pr.x = f2bf(acc[mt][nt][2 * i]);
              pr.y = f2bf(acc[mt][nt][2 * i + 1]);
              *(ushort2v*)(smem + (nt * 16 + l16) * 136 + wy * 64 + mt * 16 + quad * 4 +
                           2 * i) = pr;
            }
      }
      __syncthreads();
      #pragma unroll
      for (int jj = 0; jj < 4; ++jj) {
        int v = (tid >> 4) + jj * 16;
        int row0 = (tid & 15) * 8;
        ushort8 val = *(const ushort8*)(smem + v * 136 + row0);
        *(ushort8*)(vT + (size_t)(vbase + p * 64 + v) * 4096 + bm + row0) = val;
      }
      __syncthreads();
    }
  }
}

// A bf16 [M][K] row stride lda, Bt bf16 [N][K], C fp32. 128x64 tile,
// grid fixed (16,32) = 512 blocks, XCD 8x8 chunk (byp fastest).
// R11 2-barrier loop + R13 LDS swizzle.
__global__ __launch_bounds__(256, 2) void gemm_bt_f32out(const ushort_t* __restrict__ A,
                                                         const ushort_t* __restrict__ Bt,
                                                         float* __restrict__ C,
                                                         int M, int N, int K, int lda) {
  __shared__ __attribute__((aligned(16))) ushort_t As[128 * 64];
  __shared__ __attribute__((aligned(16))) ushort_t Bs[64 * 64];
  const int tid = threadIdx.x;
  const int lane = tid & 63;
  const int wave = tid >> 6;
  const int wy = wave >> 1, wx = wave & 1;  // wave tile: 64 rows x 32 cols
  const int quad = lane >> 4, l16 = lane & 15;
  const int bid = blockIdx.y * 16 + blockIdx.x;
  const int xcd = bid & 7, j = bid >> 3;    // j in [0,64)
  const int bxp = (xcd & 1) * 8 + (j >> 3);  // byp fastest
  const int byp = (xcd >> 1) * 8 + (j & 7);
  const size_t bm = (size_t)byp * 128;
  const size_t bn = (size_t)bxp * 64;

  const f32x4 fzero = {0.f, 0.f, 0.f, 0.f};
  f32x4 acc[4][2];
  #pragma unroll
  for (int i = 0; i < 4; ++i)
    #pragma unroll
    for (int jj = 0; jj < 2; ++jj) acc[i][jj] = fzero;

  for (int k0 = 0; k0 < K; k0 += 64) {
    #pragma unroll
    for (int i = 0; i < 4; ++i) {
      int c = (wave * 4 + i) * 64 + lane;
      int row = c >> 3, colg = c & 7;
      int scol = (colg ^ (row & 7)) * 8;
      gl_lds16(A + (bm + row) * lda + k0 + scol, As + c * 8);
    }
    #pragma unroll
    for (int i = 0; i < 2; ++i) {
      int c = (wave * 2 + i) * 64 + lane;
      int row = c >> 3, colg = c & 7;
      int scol = (colg ^ (row & 7)) * 8;
      gl_lds16(Bt + (bn + row) * K + k0 + scol, Bs + c * 8);
    }
    __syncthreads();
    #pragma unroll
    for (int ks = 0; ks < 2; ++ks) {
      bf16x8 af[4], bb[2];
      #pragma unroll
      for (int mt = 0; mt < 4; ++mt)
        af[mt] = *(const bf16x8*)(As + SWZ(wy * 64 + mt * 16 + l16, ks * 32 + quad * 8));
      #pragma unroll
      for (int nt = 0; nt < 2; ++nt)
        bb[nt] = *(const bf16x8*)(Bs + SWZ(wx * 32 + nt * 16 + l16, ks * 32 + quad * 8));
      #pragma unroll
      for (int mt = 0; mt < 4; ++mt)
        #pragma unroll
        for (int nt = 0; nt < 2; ++nt)
          acc[mt][nt] = __builtin_amdgcn_mfma_f32_16x16x32_bf16(af[mt], bb[nt], acc[mt][nt], 0, 0, 0);
    }
    __syncthreads();
  }
  #pragma unroll
  for (int mt = 0; mt < 4; ++mt)
    #pragma unroll
    for (int nt = 0; nt < 2; ++nt)
      #pragma unroll
      for (int r = 0; r < 4; ++r)
        C[(bm + wy * 64 + mt * 16 + quad * 4 + r) * N + bn + wx * 32 + nt * 16 + l16] =
            acc[mt][nt][r];
}

// Flash causal attention, k-split QK. FROZEN (R9 structure, ~73 µs floor).
// 64-row q-tile per block, 256 threads = 4 waves. grid (16 heads, 64) =
// 1024 blocks, LDS 40960B -> 4 blocks/CU, 16 waves/CU. Balanced qt mapping:
// CU gets by set {r,r+16,r+32,r+48} -> qt {r, 63-r, 16+r, 47-r}.
// Per iter: [bar1] -> QK k-split (wave w: S^T rows k in w*16..+16, all 64 q;
// 2 ak reads, Q in regs) -> stage t+1 (reg prefetch, 2-iter pipeline) ->
// exp+mask -> Ps write (cross-wave) -> [bar2] -> PV on wave's 16-q strip +
// l via all-ones-A MFMA.
__global__ __launch_bounds__(256, 4) void attn_fwd(const ushort_t* __restrict__ qkv,
                                                   const ushort_t* __restrict__ vT,
                                                   ushort_t* __restrict__ y) {
  __shared__ __attribute__((aligned(16))) ushort_t Ks[2][64 * 64];
  __shared__ __attribute__((aligned(16))) ushort_t Vt[2][64 * 64];
  __shared__ __attribute__((aligned(16))) ushort_t Ps[64 * 64];
  const int head = blockIdx.x;
  const int by = blockIdx.y;
  const int g = by >> 4, r4 = by & 15;  // balanced per-CU 4-set mapping
  const int qt = (g == 0) ? r4 : (g == 1) ? (63 - r4) : (g == 2) ? (16 + r4) : (47 - r4);
  const int qb = qt * 64;
  const int ntiles = qt + 1;
  const int tid = threadIdx.x;
  const int lane = tid & 63, wave = tid >> 6;  // 4 waves
  const int quad = lane >> 4, l16 = lane & 15;
  const int hoff = head * 64;
  const int wrow = wave * 16;                        // wave's k-rows (QK) / q-strip (PV)
  const int srow = tid >> 2, scol = (tid & 3) * 16;  // staging: 64 rows x 64 cols

  // Q fragments for ALL 64 q-rows (B-operand): bq[qtile][ks], 32 VGPRs
  bf16x8 bq[4][2];
  #pragma unroll
  for (int q2 = 0; q2 < 4; ++q2)
    #pragma unroll
    for (int ks = 0; ks < 2; ++ks)
      bq[q2][ks] = *(const bf16x8*)(qkv + (size_t)(qb + q2 * 16 + l16) * 3072 + hoff +
                                    ks * 32 + quad * 8);

  // all-ones A-frag for the l row-sum MFMA
  bf16x8 ones;
  #pragma unroll
  for (int i = 0; i < 8; ++i) ones[i] = (__bf16)1.0f;

  // stage tile 0 into buf0 (reg roundtrip; swizzled ds_write)
  ushort8 kreg[2], vreg[2];
  #pragma unroll
  for (int i = 0; i < 2; ++i) {
    kreg[i] = *(const ushort8*)(qkv + (size_t)srow * 3072 + 1024 + hoff + scol + i * 8);
    vreg[i] = *(const ushort8*)(vT + (size_t)(hoff + srow) * 4096 + scol + i * 8);
  }
  #pragma unroll
  for (int i = 0; i < 2; ++i) {
    *(ushort8*)(Ks[0] + SWZ(srow, scol + i * 8)) = kreg[i];
    *(ushort8*)(Vt[0] + SWZ(srow, scol + i * 8)) = vreg[i];
  }
  // prefetch tile 1 regs (in-bounds even when unused: rows 64..127 < 4096)
  #pragma unroll
  for (int i = 0; i < 2; ++i) {
    kreg[i] = *(const ushort8*)(qkv + (size_t)(64 + srow) * 3072 + 1024 + hoff + scol + i * 8);
    vreg[i] = *(const ushort8*)(vT + (size_t)(hoff + srow) * 4096 + 64 + scol + i * 8);
  }

  const f32x4 fzero = {0.f, 0.f, 0.f, 0.f};
  f32x4 o0[4], ol0 = fzero;
  #pragma unroll
  for (int nt = 0; nt < 4; ++nt) o0[nt] = fzero;

  for (int t = 0; t < ntiles; ++t) {
    const int cur = t & 1;
    __syncthreads();  // bar1: buf[cur] ready; Ps free (prev PV done)

    // QK k-split: S^T[k = wrow+quad*4+r][q = q2*16+l16]; only 2 ak reads
    f32x4 s[4];
    #pragma unroll
    for (int q2 = 0; q2 < 4; ++q2) s[q2] = fzero;
    bf16x8 ak[2];
    #pragma unroll
    for (int ks = 0; ks < 2; ++ks)
      ak[ks] = *(const bf16x8*)(Ks[cur] + SWZ(wrow + l16, ks * 32 + quad * 8));
    __builtin_amdgcn_s_setprio(1);
    #pragma unroll
    for (int ks = 0; ks < 2; ++ks)
      #pragma unroll
      for (int q2 = 0; q2 < 4; ++q2)
        s[q2] = __builtin_amdgcn_mfma_f32_16x16x32_bf16(ak[ks], bq[q2][ks], s[q2], 0, 0, 0);
    __builtin_amdgcn_s_setprio(0);

    // stage tile t+1 into the other buffer; then issue loads for tile t+2
    if (t + 1 < ntiles) {
      #pragma unroll
      for (int i = 0; i < 2; ++i) {
        *(ushort8*)(Ks[1 - cur] + SWZ(srow, scol + i * 8)) = kreg[i];
        *(ushort8*)(Vt[1 - cur] + SWZ(srow, scol + i * 8)) = vreg[i];
      }
      if (t + 2 < ntiles) {
        const int kb2 = (t + 2) * 64;
        #pragma unroll
        for (int i = 0; i < 2; ++i) {
          kreg[i] = *(const ushort8*)(qkv + (size_t)(kb2 + srow) * 3072 + 1024 + hoff +
                                      scol + i * 8);
          vreg[i] = *(const ushort8*)(vT + (size_t)(hoff + srow) * 4096 + kb2 + scol + i * 8);
        }
      }
    }

    // exp + causal mask; write P columns [wrow, wrow+16) for all 64 q.
    // Only the final tile (kb == qb) is masked — block-uniform.
    const int kb = t * 64;
    const bool masked = (kb + 63 > qb);
    #pragma unroll
    for (int q2 = 0; q2 < 4; ++q2) {
      float p[4];
      #pragma unroll
      for (int r = 0; r < 4; ++r) {
        float xv = s[q2][r];
        if (masked) {
          int kkg = kb + wrow + quad * 4 + r;
          xv = (kkg <= qb + q2 * 16 + l16) ? xv : -30000.f;
        }
        p[r] = fast_exp2(xv);
      }
      unsigned int u01, u23;
      asm("v_cvt_pk_bf16_f32 %0, %1, %2" : "=v"(u01) : "v"(p[0]), "v"(p[1]));
      asm("v_cvt_pk_bf16_f32 %0, %1, %2" : "=v"(u23) : "v"(p[2]), "v"(p[3]));
      uint2 pu; pu.x = u01; pu.y = u23;
      *(uint2*)(Ps + SWZ(q2 * 16 + l16, wrow + quad * 4)) = pu;
    }

    __syncthreads();  // bar2: all waves' P columns complete

    // PV on wave's q-strip: O^T += V^T P^T ; l += ones^T P^T
    __builtin_amdgcn_s_setprio(1);
    #pragma unroll
    for (int ks = 0; ks < 2; ++ks) {
      bf16x8 bp0 = *(const bf16x8*)(Ps + SWZ(wrow + l16, ks * 32 + quad * 8));
      #pragma unroll
      for (int nt = 0; nt < 4; ++nt) {
        bf16x8 av = *(const bf16x8*)(Vt[cur] + SWZ(nt * 16 + l16, ks * 32 + quad * 8));
        o0[nt] = __builtin_amdgcn_mfma_f32_16x16x32_bf16(av, bp0, o0[nt], 0, 0, 0);
      }
      ol0 = __builtin_amdgcn_mfma_f32_16x16x32_bf16(ones, bp0, ol0, 0, 0, 0);
    }
    __builtin_amdgcn_s_setprio(0);
  }

  // l[q=l16] is in every row-slot of ol0; no cross-lane reduce needed.
  const float inv0 = 1.0f / ol0[0];
  // o0[nt][r] = O[q = qb+wrow+l16][d = nt*16+quad*4+r] -> packed stores
  #pragma unroll
  for (int nt = 0; nt < 4; ++nt) {
    ushort4v ov0;
    #pragma unroll
    for (int r = 0; r < 4; ++r) ov0[r] = f2bf(o0[nt][r] * inv0);
    *(ushort4v*)(y + (size_t)(qb + wrow + l16) * 3072 + hoff + nt * 16 + quad * 4) = ov0;
  }
}

extern "C" void kernel_launch(void* const* d_in, const int* in_sizes, int n_in,
                              void* d_out, int out_size, void* d_ws, size_t ws_size,
                              hipStream_t stream) {
  const float* x = (const float*)d_in[0];       // [4096][1024] fp32
  const float* w_qkv = (const float*)d_in[1];   // [1024][3072] fp32
  const float* w_proj = (const float*)d_in[2];  // [1024][1024] fp32
  float* out = (float*)d_out;                   // [4096][1024] fp32

  ushort_t* ws = (ushort_t*)d_ws;
  ushort_t* qkv = ws;                            // [4096][3072]  [0, 24 MiB)
  ushort_t* wqkvT = ws + (size_t)4096 * 3072;    // [3072][1024]  [24, 30 MiB)
  ushort_t* wprojT = wqkvT + (size_t)3072 * 1024;  // [1024][1024] [30, 32 MiB)
  ushort_t* yb = qkv + 2048;                     // strided view into dead V cols (ld 3072)
  ushort_t* xb = (ushort_t*)d_out;               // x bf16 in d_out[0,8M)
  ushort_t* vT = (ushort_t*)d_out + (size_t)4096 * 1024;  // [1024][4096] in d_out[8M,16M)

  prep<<<8192, 256, 0, stream>>>(x, xb, w_qkv, wqkvT, w_proj, wprojT);
  gemm_bt_bf16out<<<dim3(24, 32), 256, 0, stream>>>(xb, wqkvT, qkv, vT, 4096, 3072, 1024);
  attn_fwd<<<dim3(16, 64), 256, 0, stream>>>(qkv, vT, yb);
  gemm_bt_f32out<<<dim3(16, 32), 256, 0, stream>>>(yb, wprojT, out, 4096, 1024, 1024, 3072);
}